// Round 17
// baseline (192.493 us; speedup 1.0000x reference)
//
#include <hip/hip_runtime.h>

namespace {
constexpr int CC = 3, FF = 51;
constexpr int BB = 4;
constexpr int HOUT = 384, WOUT = 384;
constexpr int HIN = 434, WIN = 434;
constexpr int KY = 4;                 // vertical outputs per thread
constexpr int LANES = 64;             // x-pixels per block
constexpr int NW = 4;                 // fx-split waves per block (13/13/13/12 taps)
constexpr int EXT = LANES + FF - 1;   // 114 valid f32 per channel strip
constexpr int LPAD = 128;             // strip pitch (f32), pow2 -> static indices
constexpr int NSTEP = FF + KY - 1;    // 54 input rows per tile (even)
constexpr int NSG = CC * LPAD / LANES;   // 6 staged f32/lane
constexpr int NTAP = 16;              // padded window taps (aw shift + 13)
constexpr int SSTRIDE = NW * CC * LPAD;  // f32 elems per LDS buffer (1536)
}  // namespace

// f32-FMA kernel. r16 analysis: all seven prior variants sat at the SAME
// effective dot2 throughput (~76 TF = exactly 1/4 of the 315 TF full-rate
// ceiling) -> v_dot2_f32_f16 is quarter-rate on gfx950 and was the wall.
// v_fma_f32 is HW-measured full-rate (2 cyc, m07). This kernel computes the
// horizontal dots with 192 f32 FMA/step instead of 96 dot2/step.
// Side effects: full f32 numerics, no cvt16 pre-kernel, no workspace.
// Structure = r6/r14-proven: NW=4 fx-split, KY=4, double-buffered f32 LDS
// staging (reg-tracked loads, no global_load_lds — r10-r12 lesson), rolled
// loop with wave-uniform tail branches (r13 lesson: no unrolled tails).
__global__ __launch_bounds__(NW* LANES, 2) void sepconv_kernel(
    const float* __restrict__ In, const float* __restrict__ Ver,
    const float* __restrict__ Hor, float* __restrict__ Out) {
  const int lane = threadIdx.x;
  const int w = threadIdx.y;          // fx-quarter
  const int x0 = blockIdx.x * LANES;
  const int y0 = blockIdx.y * KY;
  const int b = blockIdx.z;
  const int x = x0 + lane;
  const int fxBase = 13 * w;          // taps [fxBase, fxBase+ntaps)
  const int ntaps = (w < 3) ? 13 : 12;
  const int aw = (lane + fxBase) & 3;  // alignment class (f32 elems)
  const int bw = lane + fxBase - aw;   // 4-f32-aligned window base (16B for b128)

  __shared__ __align__(16) float sIn[2][NW][CC][LPAD];  // 12 KB
  __shared__ float sRed[NW - 1][CC][KY][LANES];         // 3 KB
  float* const sflat = &sIn[0][0][0][0];

  const size_t HW = (size_t)HOUT * WOUT;

  // ---- per-pixel horizontal taps, f32, alignment-shifted + zero-padded:
  // hp[t][j] corresponds to window elem bw+j; valid when u=j-aw in [0,ntaps).
  float hp[KY][NTAP];
  {
    const float* horx = Hor + (size_t)b * FF * HW + x;
#pragma unroll
    for (int t = 0; t < KY; ++t) {
      const float* hb = horx + (size_t)(y0 + t) * WOUT;
#pragma unroll
      for (int j = 0; j < NTAP; ++j) {
        const int u = j - aw;
        hp[t][j] = (u >= 0 && u < ntaps) ? hb[(size_t)(fxBase + u) * HW] : 0.0f;
      }
    }
  }

  const float* inb = In + ((size_t)b * CC * HIN + y0) * WIN + x0;
  const float* verb = Ver + (size_t)b * FF * HW + (size_t)y0 * WOUT + x;

  float acc[CC][KY] = {};
  float sv[NSG];
  float vv[KY];

  // ---- In staging, f32 (no conversion). Geometry as r6/r14:
  //   k: c = k>>1, e = lane + (k&1)*64; e >= EXT stores 0.0 (pad for the
  //   b128 window over-read, max elem bw+15 <= 117 < 128).
  //   x0 + EXT - 1 = 433 < WIN=434 -> no x guard needed.
#define STAGE_LOAD(R)                                                         \
  _Pragma("unroll") for (int k = 0; k < NSG; ++k) {                           \
    const int e = lane + (k & 1) * 64;                                        \
    const bool valid = ((k & 1) == 0) || (lane < EXT - LANES);                \
    sv[k] = valid ? inb[(size_t)((k >> 1) * HIN + (R)) * WIN + e] : 0.0f;     \
  }

#define STAGE_WRITE(BF)                                                       \
  _Pragma("unroll") for (int k = 0; k < NSG; ++k) {                           \
    const int e = lane + (k & 1) * 64;                                        \
    sflat[(BF)*SSTRIDE + (w * CC + (k >> 1)) * LPAD + e] = sv[k];             \
  }

#define VV_G(R)                                                               \
  _Pragma("unroll") for (int t = 0; t < KY; ++t) {                            \
    const int u = (R)-t;                                                      \
    vv[t] = (u >= 0 && u < FF)                                                \
                ? verb[(size_t)u * HW + (size_t)t * WOUT]                     \
                : 0.0f;                                                       \
  }

  // window: 4x ds_read_b128 (16B-aligned), then 16x4 f32 FMA per channel
#define COMPUTE(BF)                                                           \
  {                                                                           \
    _Pragma("unroll") for (int c = 0; c < CC; ++c) {                          \
      const float* rp = sflat + (BF)*SSTRIDE + (w * CC + c) * LPAD + bw;      \
      float ww[NTAP];                                                         \
      _Pragma("unroll") for (int q = 0; q < 4; ++q) {                         \
        const float4 f4 = *reinterpret_cast<const float4*>(rp + 4 * q);       \
        ww[4 * q + 0] = f4.x;                                                 \
        ww[4 * q + 1] = f4.y;                                                 \
        ww[4 * q + 2] = f4.z;                                                 \
        ww[4 * q + 3] = f4.w;                                                 \
      }                                                                       \
      float d[KY];                                                            \
      _Pragma("unroll") for (int t = 0; t < KY; ++t) d[t] = ww[0] * hp[t][0]; \
      _Pragma("unroll") for (int j = 1; j < NTAP; ++j) {                      \
        _Pragma("unroll") for (int t = 0; t < KY; ++t)                        \
          d[t] = __builtin_fmaf(ww[j], hp[t][j], d[t]);                       \
      }                                                                       \
      _Pragma("unroll") for (int t = 0; t < KY; ++t)                          \
        acc[c][t] = __builtin_fmaf(d[t], vv[t], acc[c][t]);                   \
    }                                                                         \
  }

  // ---- prologue: buf0 = row 0 ----
  STAGE_LOAD(0);
  STAGE_WRITE(0);

  // ---- main loop (r6-proven shape, f32) ----
#pragma unroll 1
  for (int r = 0; r < NSTEP; r += 2) {
    const bool more = (r + 2 < NSTEP);
    STAGE_LOAD(r + 1);          // In row r+1 (covered by COMPUTE r)
    VV_G(r);
    COMPUTE(0);                 // step r
    STAGE_WRITE(1);
    if (more) { STAGE_LOAD(r + 2); }
    VV_G(r + 1);
    COMPUTE(1);                 // step r+1
    if (more) { STAGE_WRITE(0); }
  }

  // ---- cross-wave fx reduction (4-way), then store ----
  if (w > 0) {
#pragma unroll
    for (int c = 0; c < CC; ++c)
#pragma unroll
      for (int t = 0; t < KY; ++t) sRed[w - 1][c][t][lane] = acc[c][t];
  }
  __syncthreads();
  if (w == 0) {
    float* outb = Out + (size_t)b * CC * HW + (size_t)y0 * WOUT + x0 + lane;
#pragma unroll
    for (int c = 0; c < CC; ++c)
#pragma unroll
      for (int t = 0; t < KY; ++t)
        outb[(size_t)c * HW + (size_t)t * WOUT] =
            acc[c][t] + sRed[0][c][t][lane] + sRed[1][c][t][lane] +
            sRed[2][c][t][lane];
  }
#undef STAGE_LOAD
#undef STAGE_WRITE
#undef VV_G
#undef COMPUTE
}

extern "C" void kernel_launch(void* const* d_in, const int* in_sizes, int n_in,
                              void* d_out, int out_size, void* d_ws, size_t ws_size,
                              hipStream_t stream) {
  const float* In = (const float*)d_in[0];
  const float* Ver = (const float*)d_in[1];
  const float* Hor = (const float*)d_in[2];
  float* Out = (float*)d_out;

  dim3 grid(WOUT / LANES, HOUT / KY, BB);
  dim3 block(LANES, NW, 1);
  sepconv_kernel<<<grid, block, 0, stream>>>(In, Ver, Hor, Out);
}

// Round 18
// 189.862 us; speedup vs baseline: 1.0139x; 1.0139x over previous
//
#include <hip/hip_runtime.h>

namespace {
constexpr int CC = 3, FF = 51;
constexpr int BB = 4;
constexpr int HOUT = 384, WOUT = 384;
constexpr int HIN = 434, WIN = 434;
constexpr int KY = 4;                 // vertical outputs per thread (2 packed pairs)
constexpr int LANES = 64;             // x-pixels per block
constexpr int NW = 4;                 // fx-split waves per block (13/13/13/12 taps)
constexpr int EXT = LANES + FF - 1;   // 114 valid f32 per channel strip
constexpr int LPAD = 128;             // strip pitch (f32), pow2 -> static indices
constexpr int NSTEP = FF + KY - 1;    // 54 input rows per tile (even)
constexpr int NSG = CC * LPAD / LANES;   // 6 staged f32/lane
constexpr int NTAP = 16;              // padded window taps (aw shift + 13)
constexpr int SSTRIDE = NW * CC * LPAD;  // f32 elems per LDS buffer (1536)

using v2f = float __attribute__((ext_vector_type(2)));

__device__ __forceinline__ v2f pkfma(v2f a, v2f b, v2f c) {
#if __has_builtin(__builtin_elementwise_fma)
  return __builtin_elementwise_fma(a, b, c);  // -> v_pk_fma_f32
#else
  v2f r;
  r.x = __builtin_fmaf(a.x, b.x, c.x);
  r.y = __builtin_fmaf(a.y, b.y, c.y);
  return r;
#endif
}
}  // namespace

// Packed-f32 kernel. r17 established: wall = VALU-cycle stream / (1024 *
// VALUBusy~0.6), dot2 is HALF-rate (~4cyc) on gfx950, f32 scalar FMA gives
// the same stream length. v_pk_fma_f32 (2 FMA/instr, the basis of the
// 157.3 TF f32 spec) halves the stream: pack over output-row PAIRS so there
// is no horizontal-add tail and the accumulate stays packed.
// Structure identical to r17 otherwise (f32 LDS staging, reg-tracked loads,
// no global_load_lds, rolled loop, wave-uniform tails).
__global__ __launch_bounds__(NW* LANES, 2) void sepconv_kernel(
    const float* __restrict__ In, const float* __restrict__ Ver,
    const float* __restrict__ Hor, float* __restrict__ Out) {
  const int lane = threadIdx.x;
  const int w = threadIdx.y;          // fx-quarter
  const int x0 = blockIdx.x * LANES;
  const int y0 = blockIdx.y * KY;
  const int b = blockIdx.z;
  const int x = x0 + lane;
  const int fxBase = 13 * w;          // taps [fxBase, fxBase+ntaps)
  const int ntaps = (w < 3) ? 13 : 12;
  const int aw = (lane + fxBase) & 3;  // alignment class (f32 elems)
  const int bw = lane + fxBase - aw;   // 4-f32-aligned window base (16B b128)

  __shared__ __align__(16) float sIn[2][NW][CC][LPAD];  // 12 KB
  __shared__ float sRed[NW - 1][CC][KY][LANES];         // 3 KB
  float* const sflat = &sIn[0][0][0][0];

  const size_t HW = (size_t)HOUT * WOUT;

  // ---- per-pixel horizontal taps, packed over t-pairs:
  // hpT2[j][p] = ( hp(t=2p, j), hp(t=2p+1, j) ); window elem j valid when
  // u = j-aw in [0, ntaps).
  v2f hpT2[NTAP][2];
  {
    const float* horx = Hor + (size_t)b * FF * HW + x;
#pragma unroll
    for (int j = 0; j < NTAP; ++j) {
      const int u = j - aw;
      const bool val = (u >= 0 && u < ntaps);
      const float* hb = val ? (horx + (size_t)(fxBase + u) * HW) : nullptr;
#pragma unroll
      for (int p = 0; p < 2; ++p) {
        v2f h;
        h.x = val ? hb[(size_t)(y0 + 2 * p) * WOUT] : 0.0f;
        h.y = val ? hb[(size_t)(y0 + 2 * p + 1) * WOUT] : 0.0f;
        hpT2[j][p] = h;
      }
    }
  }

  const float* inb = In + ((size_t)b * CC * HIN + y0) * WIN + x0;
  const float* verb = Ver + (size_t)b * FF * HW + (size_t)y0 * WOUT + x;

  v2f acc2[CC][2];
#pragma unroll
  for (int c = 0; c < CC; ++c) {
    acc2[c][0] = (v2f)(0.0f);
    acc2[c][1] = (v2f)(0.0f);
  }
  float sv[NSG];
  v2f vv2[2];

#define STAGE_LOAD(R)                                                         \
  _Pragma("unroll") for (int k = 0; k < NSG; ++k) {                           \
    const int e = lane + (k & 1) * 64;                                        \
    const bool valid = ((k & 1) == 0) || (lane < EXT - LANES);                \
    sv[k] = valid ? inb[(size_t)((k >> 1) * HIN + (R)) * WIN + e] : 0.0f;     \
  }

#define STAGE_WRITE(BF)                                                       \
  _Pragma("unroll") for (int k = 0; k < NSG; ++k) {                           \
    const int e = lane + (k & 1) * 64;                                        \
    sflat[(BF)*SSTRIDE + (w * CC + (k >> 1)) * LPAD + e] = sv[k];             \
  }

  // guarded Ver loads for step R, packed into vv2[p] = (vv[2p], vv[2p+1])
#define VV_G(R)                                                               \
  _Pragma("unroll") for (int p = 0; p < 2; ++p) {                             \
    _Pragma("unroll") for (int h = 0; h < 2; ++h) {                           \
      const int t = 2 * p + h;                                                \
      const int u = (R)-t;                                                    \
      const float fv = (u >= 0 && u < FF)                                     \
                           ? verb[(size_t)u * HW + (size_t)t * WOUT]          \
                           : 0.0f;                                            \
      if (h == 0) vv2[p].x = fv; else vv2[p].y = fv;                          \
    }                                                                         \
  }

  // window: 4x ds_read_b128, then 16 packed-FMA pairs per channel
#define COMPUTE(BF)                                                           \
  {                                                                           \
    _Pragma("unroll") for (int c = 0; c < CC; ++c) {                          \
      const float* rp = sflat + (BF)*SSTRIDE + (w * CC + c) * LPAD + bw;      \
      float ww[NTAP];                                                         \
      _Pragma("unroll") for (int q = 0; q < 4; ++q) {                         \
        const float4 f4 = *reinterpret_cast<const float4*>(rp + 4 * q);       \
        ww[4 * q + 0] = f4.x;                                                 \
        ww[4 * q + 1] = f4.y;                                                 \
        ww[4 * q + 2] = f4.z;                                                 \
        ww[4 * q + 3] = f4.w;                                                 \
      }                                                                       \
      v2f d0, d1;                                                             \
      {                                                                       \
        v2f s0;                                                               \
        s0.x = ww[0]; s0.y = ww[0];                                           \
        d0 = s0 * hpT2[0][0];                                                 \
        d1 = s0 * hpT2[0][1];                                                 \
      }                                                                       \
      _Pragma("unroll") for (int j = 1; j < NTAP; ++j) {                      \
        v2f s;                                                                \
        s.x = ww[j]; s.y = ww[j];                                             \
        d0 = pkfma(s, hpT2[j][0], d0);                                        \
        d1 = pkfma(s, hpT2[j][1], d1);                                        \
      }                                                                       \
      acc2[c][0] = pkfma(d0, vv2[0], acc2[c][0]);                             \
      acc2[c][1] = pkfma(d1, vv2[1], acc2[c][1]);                             \
    }                                                                         \
  }

  // ---- prologue: buf0 = row 0 ----
  STAGE_LOAD(0);
  STAGE_WRITE(0);

  // ---- main loop (r6-proven shape) ----
#pragma unroll 1
  for (int r = 0; r < NSTEP; r += 2) {
    const bool more = (r + 2 < NSTEP);
    STAGE_LOAD(r + 1);          // In row r+1 (covered by COMPUTE r)
    VV_G(r);
    COMPUTE(0);                 // step r
    STAGE_WRITE(1);
    if (more) { STAGE_LOAD(r + 2); }
    VV_G(r + 1);
    COMPUTE(1);                 // step r+1
    if (more) { STAGE_WRITE(0); }
  }

  // ---- cross-wave fx reduction (4-way), then store ----
  if (w > 0) {
#pragma unroll
    for (int c = 0; c < CC; ++c)
#pragma unroll
      for (int p = 0; p < 2; ++p) {
        sRed[w - 1][c][2 * p + 0][lane] = acc2[c][p].x;
        sRed[w - 1][c][2 * p + 1][lane] = acc2[c][p].y;
      }
  }
  __syncthreads();
  if (w == 0) {
    float* outb = Out + (size_t)b * CC * HW + (size_t)y0 * WOUT + x0 + lane;
#pragma unroll
    for (int c = 0; c < CC; ++c)
#pragma unroll
      for (int p = 0; p < 2; ++p) {
        const float a0 = acc2[c][p].x + sRed[0][c][2 * p][lane] +
                         sRed[1][c][2 * p][lane] + sRed[2][c][2 * p][lane];
        const float a1 = acc2[c][p].y + sRed[0][c][2 * p + 1][lane] +
                         sRed[1][c][2 * p + 1][lane] + sRed[2][c][2 * p + 1][lane];
        outb[(size_t)c * HW + (size_t)(2 * p) * WOUT] = a0;
        outb[(size_t)c * HW + (size_t)(2 * p + 1) * WOUT] = a1;
      }
  }
#undef STAGE_LOAD
#undef STAGE_WRITE
#undef VV_G
#undef COMPUTE
}

extern "C" void kernel_launch(void* const* d_in, const int* in_sizes, int n_in,
                              void* d_out, int out_size, void* d_ws, size_t ws_size,
                              hipStream_t stream) {
  const float* In = (const float*)d_in[0];
  const float* Ver = (const float*)d_in[1];
  const float* Hor = (const float*)d_in[2];
  float* Out = (float*)d_out;

  dim3 grid(WOUT / LANES, HOUT / KY, BB);
  dim3 block(LANES, NW, 1);
  sepconv_kernel<<<grid, block, 0, stream>>>(In, Ver, Hor, Out);
}